// Round 5
// baseline (196.759 us; speedup 1.0000x reference)
//
#include <hip/hip_runtime.h>
#include <hip/hip_bf16.h>

#define B_ 4
#define C_ 128
#define H_ 96
#define W_ 96
#define MD 20
#define K41 41
#define OH 48
#define OW 48
#define HW_ (H_ * W_)
#define NJ 5
#define NG 9                      // ceil(41/NJ)
#define NBLK (NG * OH * B_)       // 1728 (divisible by 8)

using bf16x8 = __attribute__((ext_vector_type(8))) short;
using f32x4v = __attribute__((ext_vector_type(4))) float;

__device__ __forceinline__ unsigned short f2bf(float f) {   // RNE fp32->bf16
    unsigned int u = __float_as_uint(f);
    return (unsigned short)((u + 0x7fff + ((u >> 16) & 1)) >> 16);
}

// Pool one Gram's D-fragments into racc[JL][nt][rp].
// term1 = D[m][u] (even m = 16wv+4hi+2rp), term2 = D[m+1][u+1] via lane+1 shfl.
#define POOL(ACC, JL)                                                          \
  {                                                                            \
    _Pragma("unroll")                                                          \
    for (int rp = 0; rp < 2; ++rp) {                                           \
      float nx[4];                                                             \
      _Pragma("unroll")                                                        \
      for (int nt = 0; nt < 4; ++nt)                                           \
        nx[nt] = __shfl(ACC[nt][2 * rp + 1],                                   \
                        (lane & 48) | ((lane + 1) & 15), 64);                  \
      _Pragma("unroll")                                                        \
      for (int nt = 0; nt < 4; ++nt) {                                         \
        int u = ubase + nt * 16 + ul;                                          \
        float t1 = (u >= 0 && u <= 95) ? ACC[nt][2 * rp] : 0.f;                \
        float t2n = (ul < 15) ? nx[nt] : (nt < 3 ? nx[nt + 1] : 0.f);          \
        float t2 = (u >= -1 && u <= 94) ? t2n : 0.f;                           \
        racc[JL][nt][rp] += t1 + t2;                                           \
      }                                                                        \
    }                                                                          \
  }

__global__ __launch_bounds__(384, 3) void corr_fused(
    const float* __restrict__ x1, const float* __restrict__ x2,
    float* __restrict__ out) {
  // XCD-bijective swizzle: consecutive HW bids (round-robin XCDs) -> contiguous
  // logical chunks per XCD so (b, oy)-neighbors share x2 rows in one L2.
  const int bid = blockIdx.x;
  const int l = (bid & 7) * (NBLK / 8) + (bid >> 3);
  const int jg = l % NG;
  const int rest = l / NG;
  const int oy = rest % OH;
  const int b = rest / OH;
  const int j0 = jg * NJ;
  const int NJv = min(NJ, K41 - j0);   // valid j count in this group
  const int y1 = oy * 2;

  __shared__ __align__(16) char smem[49152];
  short* x2s = (short*)smem;           // [2][12288] bf16, swizzled [u][c]
  float* obuf = (float*)smem;          // reused after row loop

  const int tid = threadIdx.x, wv = tid / 64, lane = tid & 63;
  const int ul = lane & 15, hi = lane >> 4;
  const int mcol = wv * 16 + ul;       // A row (x position)
  const int ubase = wv * 16 - 24;      // band origin for this wave

  // ---- A fragments gathered from raw x1 (c = k*32 + hi*8 + e) ----
  bf16x8 a[2][4];
  {
    const float* p1 = x1 + (size_t)b * C_ * HW_ + (size_t)y1 * W_ + mcol;
#pragma unroll
    for (int p = 0; p < 2; ++p)
#pragma unroll
      for (int k = 0; k < 4; ++k) {
        const float* pc = p1 + p * W_ + (size_t)(k * 32 + hi * 8) * HW_;
#pragma unroll
        for (int e = 0; e < 8; ++e)
          a[p][k][e] = (short)f2bf(pc[(size_t)e * HW_]);
      }
  }

  // ---- staging helpers: thread owns (cg = tid/24: 8 c's) x (uq = tid%24: 4 u's)
  const int uq = tid % 24;
  const int cg = tid / 24;
  const float* x2base = x2 + (size_t)b * C_ * HW_;

  auto stage_load = [&](int r, f32x4v st[8]) {
    const float* src = x2base + (size_t)cg * 8 * HW_ + r * W_ + uq * 4;
#pragma unroll
    for (int e = 0; e < 8; ++e)
      st[e] = *(const f32x4v*)(src + (size_t)e * HW_);
  };
  auto stage_write = [&](int half, const f32x4v st[8], bool valid) {
    char* base = (char*)(x2s + half * 12288);
#pragma unroll
    for (int uu = 0; uu < 4; ++uu) {
      int u = uq * 4 + uu;
      int addr = (u * 256 + cg * 16) ^ ((u & 7) << 4);
      bf16x8 v = {0, 0, 0, 0, 0, 0, 0, 0};
      if (valid) {
#pragma unroll
        for (int e = 0; e < 8; ++e) v[e] = (short)f2bf(st[e][uu]);
      }
      *(bf16x8*)(base + addr) = v;
    }
  };

  float racc[NJ][4][2] = {};
  const int r0 = y1 + j0 - MD;

  // prologue: stage row 0 into buf0
  {
    f32x4v st[8];
    bool v = (r0 >= 0 && r0 < H_);
    if (v) stage_load(r0, st);
    stage_write(0, st, v);
  }
  __syncthreads();

#pragma unroll
  for (int kr = 0; kr <= NJ; ++kr) {
    if (kr > NJv) break;               // uniform
    // phase A: issue next row's global loads (latency hides under compute)
    f32x4v st[8];
    bool nv = false;
    if (kr < NJv) {
      int rn = r0 + kr + 1;
      nv = (rn >= 0 && rn < H_);
      if (nv) stage_load(rn, st);
    }
    // phase B: banded Gram on buf[kr&1]; B-frags shared by both y-rows
    const short* buf = x2s + (kr & 1) * 12288;
    const bool g0 = (kr < NJv);        // p=0 -> jl = kr
    const bool g1 = (kr >= 1);         // p=1 -> jl = kr-1
    f32x4v acc0[4], acc1[4];
#pragma unroll
    for (int nt = 0; nt < 4; ++nt) {
      int u = ubase + nt * 16 + ul;
      int ur = u < 0 ? 0 : (u > 95 ? 95 : u);
      acc0[nt] = (f32x4v){0.f, 0.f, 0.f, 0.f};
      acc1[nt] = (f32x4v){0.f, 0.f, 0.f, 0.f};
#pragma unroll
      for (int k = 0; k < 4; ++k) {
        int ba = (ur * 256 + k * 64 + hi * 16) ^ ((ur & 7) << 4);
        bf16x8 bfr = *(const bf16x8*)((const char*)buf + ba);
        if (g0) acc0[nt] = __builtin_amdgcn_mfma_f32_16x16x32_bf16(a[0][k], bfr, acc0[nt], 0, 0, 0);
        if (g1) acc1[nt] = __builtin_amdgcn_mfma_f32_16x16x32_bf16(a[1][k], bfr, acc1[nt], 0, 0, 0);
      }
    }
    if (g0) POOL(acc0, kr)
    if (g1) POOL(acc1, (kr - 1))
    // phase C: convert + write next row into the other buffer
    if (kr < NJv) stage_write((kr + 1) & 1, st, nv);
    __syncthreads();
  }

  // ---- scatter racc -> obuf (x2s dead), then coalesced store ----
#pragma unroll
  for (int jl = 0; jl < NJ; ++jl) {
    if (jl >= NJv) break;              // uniform
#pragma unroll
    for (int nt = 0; nt < 4; ++nt)
#pragma unroll
      for (int rp = 0; rp < 2; ++rp) {
        int i = nt * 16 + ul - 4 * hi - 2 * rp - 4;
        if (i >= 0 && i <= 40) {
          int ox = wv * 8 + 2 * hi + rp;
          obuf[jl * 2009 + i * 49 + ox] = racc[jl][nt][rp];
        }
      }
  }
  __syncthreads();
#pragma unroll
  for (int jl = 0; jl < NJ; ++jl) {
    if (jl >= NJv) break;              // uniform
    int j = j0 + jl;
#pragma unroll
    for (int s = 0; s < 6; ++s) {
      int e = tid + s * 384;
      if (e < K41 * OW) {
        int i = e / OW, ox = e - i * OW;
        out[(((size_t)b * (K41 * K41) + i * K41 + j) * OH + oy) * OW + ox] =
            obuf[jl * 2009 + i * 49 + ox] * (1.f / 512.f);
      }
    }
  }
}

extern "C" void kernel_launch(void* const* d_in, const int* in_sizes, int n_in,
                              void* d_out, int out_size, void* d_ws, size_t ws_size,
                              hipStream_t stream) {
  const float* x1 = (const float*)d_in[0];
  const float* x2 = (const float*)d_in[1];
  float* out = (float*)d_out;
  corr_fused<<<NBLK, 384, 0, stream>>>(x1, x2, out);
}

// Round 6
// 166.614 us; speedup vs baseline: 1.1809x; 1.1809x over previous
//
#include <hip/hip_runtime.h>
#include <hip/hip_bf16.h>

#define B_ 4
#define C_ 128
#define H_ 96
#define W_ 96
#define MD 20
#define K41 41
#define OH 48
#define OW 48
#define HW_ (H_ * W_)
#define TSZ ((size_t)B_ * H_ * W_ * C_)   // elements per transposed tensor
#define NBLK (K41 * OH * B_)              // 7872 = 8 * 984

using bf16x8 = __attribute__((ext_vector_type(8))) short;
using f32x4v = __attribute__((ext_vector_type(4))) float;

__device__ __forceinline__ unsigned short f2bf(float f) {   // RNE fp32->bf16
    unsigned int u = __float_as_uint(f);
    return (unsigned short)((u + 0x7fff + ((u >> 16) & 1)) >> 16);
}

__device__ __forceinline__ void async_load16(const void* g, void* l) {
    __builtin_amdgcn_global_load_lds(
        (const __attribute__((address_space(1))) unsigned int*)g,
        (__attribute__((address_space(3))) unsigned int*)l, 16, 0, 0);
}

// ---------------------------------------------------------------------------
// K1: both tensors [B][C][H][W] f32 -> [B][H][W][C] bf16, packed 16B stores.
// grid (H_, 1, 2*B_), block 256.  (measured ~16 us in round 3)
// ---------------------------------------------------------------------------
__global__ __launch_bounds__(256) void transpose_convert(
    const float* __restrict__ x1, const float* __restrict__ x2,
    short* __restrict__ x1t, short* __restrict__ x2t) {
    const int y  = blockIdx.x;
    const int zb = blockIdx.z;
    const int b  = zb & 3;
    const float* src = (zb & 4 ? x2 : x1) + (size_t)b * C_ * HW_ + (size_t)y * W_;
    short* dst = (zb & 4 ? x2t : x1t) + ((size_t)b * H_ + y) * W_ * C_;
    const int tid = threadIdx.x;
#pragma unroll
    for (int t = 0; t < 6; ++t) {
        int idx = t * 256 + tid;            // [0, 1536): 16 cgq x 96 x
        int cgq = idx / 96;
        int x   = idx - cgq * 96;
        const float* s0 = src + (size_t)(cgq * 8) * HW_ + x;
        bf16x8 pk;
#pragma unroll
        for (int e = 0; e < 8; ++e)
            pk[e] = (short)f2bf(s0[(size_t)e * HW_]);
        *(bf16x8*)(dst + x * C_ + cgq * 8) = pk;
    }
}

// ---------------------------------------------------------------------------
// K2: block per (j, oy, b) = 7872. 6 waves; wave w owns x in [16w,16w+16),
// ox in [8w,8w+8). Both x2 rows staged upfront via global_load_lds (async,
// one drain barrier); banded Gram 4x16 tiles; pooling in registers (shfl);
// output through obuf overlay for coalesced stores. 3 barriers total.
// ---------------------------------------------------------------------------
__global__ __launch_bounds__(384, 5) void corr_mfma(
    const short* __restrict__ x1t, const short* __restrict__ x2t,
    float* __restrict__ out) {
  // XCD swizzle: consecutive logical ids = consecutive j (same oy,b) per XCD.
  const int bid = blockIdx.x;
  const int l = (bid & 7) * (NBLK / 8) + (bid >> 3);
  const int j = l % K41;
  const int rest = l / K41;
  const int oy = rest % OH;
  const int b = rest / OH;
  const int y1 = oy * 2;

  __shared__ __align__(16) char smem[49152];  // 2 x 24576 row bufs; obuf overlay
  float* obuf = (float*)smem;

  const int tid = threadIdx.x, wv = tid / 64, lane = tid & 63;
  const int ul = lane & 15, hi = lane >> 4;
  const int ubase = wv * 16 - 24;             // band origin for this wave

  // ---- A fragments: 8 x bf16x8 from pre-converted x1t ----
  bf16x8 a[2][4];
  const short* x1b =
      x1t + (((size_t)b * H_ + y1) * W_ + (wv * 16 + ul)) * C_ + hi * 8;
#pragma unroll
  for (int p = 0; p < 2; ++p)
#pragma unroll
    for (int k = 0; k < 4; ++k)
      a[p][k] = *(const bf16x8*)(x1b + p * (W_ * C_) + k * 32);

  // ---- stage BOTH x2 rows upfront (async; linear LDS dest, swizzled src) ----
#pragma unroll
  for (int p = 0; p < 2; ++p) {
    const int r = y1 + p + j - MD;
    char* ldsb = smem + p * 24576;
    if (r >= 0 && r < H_) {
      const char* src = (const char*)(x2t + ((size_t)b * H_ + r) * (W_ * C_));
#pragma unroll
      for (int it = 0; it < 4; ++it) {
        const int basei = (it * 6 + wv) << 10;     // wave-uniform LDS base
        const int d = basei | (lane << 4);
        const int so = d ^ (((d >> 8) & 7) << 4);  // inverse swizzle on source
        async_load16(src + so, ldsb + basei);
      }
    } else {
      bf16x8 z = {0, 0, 0, 0, 0, 0, 0, 0};
#pragma unroll
      for (int it = 0; it < 4; ++it)
        *(bf16x8*)(ldsb + ((it * 384 + tid) << 4)) = z;
    }
  }
  __syncthreads();   // drains vmcnt: both rows resident

  float racc[4][2] = {};
#pragma unroll
  for (int p = 0; p < 2; ++p) {
    const char* buf = smem + p * 24576;
    f32x4v acc[4];
#pragma unroll
    for (int nt = 0; nt < 4; ++nt) {
      int u = ubase + nt * 16 + ul;
      int ur = u < 0 ? 0 : (u > 95 ? 95 : u);      // clamp; garbage never pooled
      acc[nt] = (f32x4v){0.f, 0.f, 0.f, 0.f};
#pragma unroll
      for (int k = 0; k < 4; ++k) {
        int ba = (ur * 256 + k * 64 + hi * 16) ^ ((ur & 7) << 4);
        bf16x8 bfr = *(const bf16x8*)(buf + ba);
        acc[nt] = __builtin_amdgcn_mfma_f32_16x16x32_bf16(a[p][k], bfr, acc[nt], 0, 0, 0);
      }
    }
    // ---- register pooling: racc += D[m][u] + D[m+1][u+1] (r5-verified) ----
#pragma unroll
    for (int rp = 0; rp < 2; ++rp) {
      float nx[4];
#pragma unroll
      for (int nt = 0; nt < 4; ++nt)
        nx[nt] = __shfl(acc[nt][2 * rp + 1], (lane & 48) | ((lane + 1) & 15), 64);
#pragma unroll
      for (int nt = 0; nt < 4; ++nt) {
        int u = ubase + nt * 16 + ul;
        float t1 = (u >= 0 && u <= 95) ? acc[nt][2 * rp] : 0.f;
        float t2n = (ul < 15) ? nx[nt] : (nt < 3 ? nx[nt + 1] : 0.f);
        float t2 = (u >= -1 && u <= 94) ? t2n : 0.f;
        racc[nt][rp] += t1 + t2;
      }
    }
  }

  __syncthreads();   // row bufs dead; overlay obuf
#pragma unroll
  for (int nt = 0; nt < 4; ++nt)
#pragma unroll
    for (int rp = 0; rp < 2; ++rp) {
      int i = nt * 16 + ul - 4 * hi - 2 * rp - 4;
      if (i >= 0 && i <= 40)
        obuf[i * 49 + (wv * 8 + 2 * hi + rp)] = racc[nt][rp];
    }
  __syncthreads();
#pragma unroll
  for (int s = 0; s < 6; ++s) {
    int e = tid + s * 384;
    if (e < K41 * OW) {
      int i = e / OW, ox = e - i * OW;
      out[(((size_t)b * (K41 * K41) + i * K41 + j) * OH + oy) * OW + ox] =
          obuf[i * 49 + ox] * (1.f / 512.f);
    }
  }
}

// ---------------------------------------------------------------------------
// Fallback (ws too small): naive fp32, one thread per output
// ---------------------------------------------------------------------------
__global__ void corr_naive(const float* __restrict__ x1, const float* __restrict__ x2,
                           float* __restrict__ out, int total) {
    int idx = blockIdx.x * 256 + threadIdx.x;
    if (idx >= total) return;
    int ox = idx % OW;
    int t  = idx / OW;
    int oy = t % OH;  t /= OH;
    int d  = t % (K41 * K41);
    int b  = t / (K41 * K41);
    int i = d / K41, jj = d - i * K41;
    float sum = 0.f;
    for (int p = 0; p < 2; ++p)
        for (int q = 0; q < 2; ++q) {
            int y = 2 * oy + p, x = 2 * ox + q;
            int r = y + jj - MD, u = x + i - MD;
            if (r < 0 || r >= H_ || u < 0 || u >= W_) continue;
            const float* p1 = x1 + ((size_t)b * C_ * HW_ + y * W_) + x;
            const float* p2 = x2 + ((size_t)b * C_ * HW_ + r * W_) + u;
            for (int c = 0; c < C_; ++c)
                sum += p1[(size_t)c * HW_] * p2[(size_t)c * HW_];
        }
    out[idx] = sum * (1.f / 512.f);
}

extern "C" void kernel_launch(void* const* d_in, const int* in_sizes, int n_in,
                              void* d_out, int out_size, void* d_ws, size_t ws_size,
                              hipStream_t stream) {
    const float* x1 = (const float*)d_in[0];
    const float* x2 = (const float*)d_in[1];
    float* out = (float*)d_out;

    const size_t need = 2 * TSZ * sizeof(short);    // 18,874,368 B
    if (ws_size >= need && d_ws != nullptr) {
        short* x1t = (short*)d_ws;
        short* x2t = x1t + TSZ;
        transpose_convert<<<dim3(H_, 1, 2 * B_), 256, 0, stream>>>(x1, x2, x1t, x2t);
        corr_mfma<<<NBLK, 384, 0, stream>>>(x1t, x2t, out);
    } else {
        int total = B_ * K41 * K41 * OH * OW;
        corr_naive<<<(total + 255) / 256, 256, 0, stream>>>(x1, x2, out, total);
    }
}